// Round 5
// baseline (573.144 us; speedup 1.0000x reference)
//
#include <hip/hip_runtime.h>
#include <hip/hip_bf16.h>

#define NH 12
constexpr float SCALE = 0.17677669529663687f;  // 1/sqrt(32)

using f32x4  = __attribute__((ext_vector_type(4))) float;
using bf16x8 = __attribute__((ext_vector_type(8))) __bf16;

// ---------------- K0: weight bf16 conversion + bias table [12][64 i][64 j] ----
// biasI[h][i][j]: j>=49 -> -1e30 (mask padded keys), i>=49 -> 0 (don't care).
__global__ __launch_bounds__(256) void wa_prep(
    const float* __restrict__ qkv_w, const float* __restrict__ proj_w,
    const float* __restrict__ tbl,
    __bf16* __restrict__ qkv_w_bf, __bf16* __restrict__ proj_w_bf,
    float* __restrict__ biasI) {
  int p = blockIdx.x * 256 + threadIdx.x;
  if (p < 442368) { qkv_w_bf[p] = (__bf16)qkv_w[p]; return; }
  p -= 442368;
  if (p < 147456) { proj_w_bf[p] = (__bf16)proj_w[p]; return; }
  p -= 147456;
  if (p >= 49152) return;
  int h = p >> 12, rem = p & 4095, i = rem >> 6, j = rem & 63;
  float v;
  if (j >= 49) v = -1e30f;
  else if (i >= 49) v = 0.0f;
  else {
    int py = i / 7, px = i % 7, qy = j / 7, qx = j % 7;
    v = tbl[((py - qy + 6) * 13 + (px - qx + 6)) * NH + h];
  }
  biasI[p] = v;
}

// half-exchange: C-frag pair (rows 0-15 in lo, 16-31 in hi; lane holds col=lr,
// rows 4*ls+r) -> operand frag (lane holds that col's k-rows 8*ls..8*ls+7).
__device__ inline bf16x8 half_ex(f32x4 lo, f32x4 hi, int srcA, int srcB, bool sel) {
  bf16x8 o;
  #pragma unroll
  for (int e = 0; e < 4; ++e) {
    float a0 = __shfl(lo[e], srcA, 64);
    float a1 = __shfl(hi[e], srcA, 64);
    float b0 = __shfl(lo[e], srcB, 64);
    float b1 = __shfl(hi[e], srcB, 64);
    o[e]     = (__bf16)(sel ? a1 : a0);
    o[e + 4] = (__bf16)(sel ? b1 : b0);
  }
  return o;
}

#define MFMA(a, b, c) __builtin_amdgcn_mfma_f32_16x16x32_bf16(a, b, c, 0, 0, 0)

// ---------------- fused: qkv GEMM + attention + proj, 1 block = 1 window ------
// 4 waves; wave wv owns heads {wv, wv+4, wv+8}. Per head: compute Q^T,K^T
// (=W@x^T) and V (=x@Wv^T) with operands read row-major (x from As LDS, W from
// L2); convert C-frags to attn operands via half_ex; swapped QK^T (S^T) so the
// P->PV conversion is the same primitive (no P/V LDS, no barriers in the head
// loop); denom via 2 shfl_xor; H -> Hs LDS. One barrier, then per-wave proj
// (96 cols) with Wp read direct from L2. 2 barriers/block total.
__global__ __launch_bounds__(256, 2) void wa_fused(
    const float* __restrict__ x, const __bf16* __restrict__ wqkv,
    const float* __restrict__ qkv_b, const __bf16* __restrict__ wp,
    const float* __restrict__ proj_b, const float* __restrict__ biasI,
    float* __restrict__ out) {
  __shared__ __bf16 As[49 * 384];   // 36.75KB x-tile, chunk^(row&7) swizzle
  __shared__ __bf16 Hs[49 * 384];   // 36.75KB head-output tile, same swizzle
  const int t = threadIdx.x, lane = t & 63, wv = t >> 6;
  const int lr = lane & 15, ls = lane >> 4;
  const int w = blockIdx.x, w49 = w * 49;
  const int srcA = (lane & 15) | ((lane & 16) << 1);
  const int srcB = srcA + 16;
  const bool sel = (lane & 32) != 0;
  const f32x4 zero = {0.f, 0.f, 0.f, 0.f};

  // stage x -> As (fp32 -> bf16)
  for (int p = t; p < 2352; p += 256) {
    int row = p / 48, c = p - row * 48;
    const float* src = x + (size_t)(w49 + row) * 384 + c * 8;
    float4 a = *(const float4*)src;
    float4 b = *(const float4*)(src + 4);
    bf16x8 o;
    o[0] = (__bf16)a.x; o[1] = (__bf16)a.y; o[2] = (__bf16)a.z; o[3] = (__bf16)a.w;
    o[4] = (__bf16)b.x; o[5] = (__bf16)b.y; o[6] = (__bf16)b.z; o[7] = (__bf16)b.w;
    int cw = (c & ~7) | ((c & 7) ^ (row & 7));
    *(bf16x8*)(As + row * 384 + cw * 8) = o;
  }
  __syncthreads();

  for (int hi = 0; hi < 3; ++hi) {
    const int h = wv + hi * 4;
    // ---- QKV GEMMs: cq/ck[d-tile][tok-tile], cv[tok-tile][d-tile]
    f32x4 cq[2][4] = {}, ck[2][4] = {}, cv[4][2] = {};
    for (int ks = 0; ks < 12; ++ks) {
      bf16x8 xa[4];
      #pragma unroll
      for (int nt = 0; nt < 4; ++nt) {
        int tok = nt * 16 + lr; if (tok > 48) tok = 48;   // clamp pad rows
        int c = ks * 4 + ls;
        int cw = (c & ~7) | ((c & 7) ^ (tok & 7));
        xa[nt] = *(const bf16x8*)(As + tok * 384 + cw * 8);
      }
      bf16x8 wq[2], wk[2], wvb[2];
      #pragma unroll
      for (int mt = 0; mt < 2; ++mt) {
        int d = h * 32 + mt * 16 + lr;
        size_t off = (size_t)ks * 32 + ls * 8;
        wq[mt]  = *(const bf16x8*)(wqkv + (size_t)d * 384 + off);
        wk[mt]  = *(const bf16x8*)(wqkv + (size_t)(384 + d) * 384 + off);
        wvb[mt] = *(const bf16x8*)(wqkv + (size_t)(768 + d) * 384 + off);
      }
      #pragma unroll
      for (int mt = 0; mt < 2; ++mt)
        #pragma unroll
        for (int nt = 0; nt < 4; ++nt) {
          cq[mt][nt] = MFMA(wq[mt], xa[nt], cq[mt][nt]);
          ck[mt][nt] = MFMA(wk[mt], xa[nt], ck[mt][nt]);
        }
      #pragma unroll
      for (int mt = 0; mt < 4; ++mt)
        #pragma unroll
        for (int nt = 0; nt < 2; ++nt)
          cv[mt][nt] = MFMA(xa[mt], wvb[nt], cv[mt][nt]);
    }
    // ---- qkv biases (cq/ck rows = d = 16mt+4ls+r; cv cols = d = 16nt+lr)
    #pragma unroll
    for (int mt = 0; mt < 2; ++mt) {
      float4 bq = *(const float4*)(qkv_b + h * 32 + mt * 16 + ls * 4);
      float4 bk = *(const float4*)(qkv_b + 384 + h * 32 + mt * 16 + ls * 4);
      #pragma unroll
      for (int nt = 0; nt < 4; ++nt)
        #pragma unroll
        for (int r = 0; r < 4; ++r) {
          cq[mt][nt][r] += ((const float*)&bq)[r];
          ck[mt][nt][r] += ((const float*)&bk)[r];
        }
    }
    #pragma unroll
    for (int nt = 0; nt < 2; ++nt) {
      float bv = qkv_b[768 + h * 32 + nt * 16 + lr];
      #pragma unroll
      for (int mt = 0; mt < 4; ++mt)
        #pragma unroll
        for (int r = 0; r < 4; ++r) cv[mt][nt][r] += bv;
    }
    // ---- convert to attn operands: ka (lane=key j), qb (lane=query i)
    bf16x8 ka[4], qb[4];
    #pragma unroll
    for (int nt = 0; nt < 4; ++nt) {
      qb[nt] = half_ex(cq[0][nt], cq[1][nt], srcA, srcB, sel);
      ka[nt] = half_ex(ck[0][nt], ck[1][nt], srcA, srcB, sel);
    }
    // ---- S^T = K @ Q^T (rows j, cols i), one k-step (d=32)
    f32x4 st[4][4];
    #pragma unroll
    for (int mt = 0; mt < 4; ++mt)
      #pragma unroll
      for (int nt = 0; nt < 4; ++nt)
        st[mt][nt] = MFMA(ka[mt], qb[nt], zero);
    // ---- bias + exp (max-free; masked keys -> -1e30 -> 0)
    #pragma unroll
    for (int mt = 0; mt < 4; ++mt)
      #pragma unroll
      for (int nt = 0; nt < 4; ++nt) {
        int i = nt * 16 + lr;
        float4 bi = *(const float4*)(biasI + ((size_t)h * 64 + i) * 64 + mt * 16 + ls * 4);
        #pragma unroll
        for (int r = 0; r < 4; ++r)
          st[mt][nt][r] = __expf(fmaf(st[mt][nt][r], SCALE, ((const float*)&bi)[r]));
      }
    // ---- P^T operand frags + row sums
    bf16x8 pb[2][4];
    float s[4] = {0.f, 0.f, 0.f, 0.f};
    #pragma unroll
    for (int k2 = 0; k2 < 2; ++k2)
      #pragma unroll
      for (int nt = 0; nt < 4; ++nt) {
        pb[k2][nt] = half_ex(st[2 * k2][nt], st[2 * k2 + 1][nt], srcA, srcB, sel);
        #pragma unroll
        for (int e = 0; e < 8; ++e) s[nt] += (float)pb[k2][nt][e];
      }
    #pragma unroll
    for (int nt = 0; nt < 4; ++nt) {
      s[nt] += __shfl_xor(s[nt], 16, 64);
      s[nt] += __shfl_xor(s[nt], 32, 64);
    }
    // ---- V^T operand frags (lane = d), PV^T: out^T[d,i], k-dim = j (2 steps)
    bf16x8 va[2][2];
    #pragma unroll
    for (int ct = 0; ct < 2; ++ct)
      #pragma unroll
      for (int k2 = 0; k2 < 2; ++k2)
        va[ct][k2] = half_ex(cv[2 * k2][ct], cv[2 * k2 + 1][ct], srcA, srcB, sel);
    f32x4 ot[2][4] = {};
    #pragma unroll
    for (int k2 = 0; k2 < 2; ++k2)
      #pragma unroll
      for (int ct = 0; ct < 2; ++ct)
        #pragma unroll
        for (int nt = 0; nt < 4; ++nt)
          ot[ct][nt] = MFMA(va[ct][k2], pb[k2][nt], ot[ct][nt]);
    // ---- normalize, convert H^T -> proj-A layout, write Hs
    #pragma unroll
    for (int nt = 0; nt < 4; ++nt) {
      float inv = 1.0f / s[nt];
      f32x4 h0, h1;
      #pragma unroll
      for (int r = 0; r < 4; ++r) { h0[r] = ot[0][nt][r] * inv; h1[r] = ot[1][nt][r] * inv; }
      bf16x8 pa = half_ex(h0, h1, srcA, srcB, sel);
      int i = nt * 16 + lr;
      if (i < 49) {
        int c = h * 4 + ls;
        int cw = (c & ~7) | ((c & 7) ^ (i & 7));
        *(bf16x8*)(Hs + i * 384 + cw * 8) = pa;
      }
    }
  }
  __syncthreads();  // Hs complete (all heads, all waves)

  // ---- proj: out[:, wv*96 .. +95] = Hs @ Wp^T + b, K = 384 (12 steps)
  f32x4 acc[4][6] = {};
  for (int ks = 0; ks < 12; ++ks) {
    bf16x8 ha[4], wb[6];
    #pragma unroll
    for (int it = 0; it < 4; ++it) {
      int tok = it * 16 + lr; if (tok > 48) tok = 48;
      int c = ks * 4 + ls;
      int cw = (c & ~7) | ((c & 7) ^ (tok & 7));
      ha[it] = *(const bf16x8*)(Hs + tok * 384 + cw * 8);
    }
    #pragma unroll
    for (int ct = 0; ct < 6; ++ct) {
      int n = wv * 96 + ct * 16 + lr;
      wb[ct] = *(const bf16x8*)(wp + (size_t)n * 384 + ks * 32 + ls * 8);
    }
    #pragma unroll
    for (int it = 0; it < 4; ++it)
      #pragma unroll
      for (int ct = 0; ct < 6; ++ct)
        acc[it][ct] = MFMA(ha[it], wb[ct], acc[it][ct]);
  }
  float pbias[6];
  #pragma unroll
  for (int ct = 0; ct < 6; ++ct) pbias[ct] = proj_b[wv * 96 + ct * 16 + lr];
  #pragma unroll
  for (int it = 0; it < 4; ++it)
    #pragma unroll
    for (int r = 0; r < 4; ++r) {
      int i = it * 16 + ls * 4 + r;
      if (i < 49) {
        float* dst = out + (size_t)(w49 + i) * 384 + wv * 96;
        #pragma unroll
        for (int ct = 0; ct < 6; ++ct)
          dst[ct * 16 + lr] = acc[it][ct][r] + pbias[ct];
      }
    }
}

extern "C" void kernel_launch(void* const* d_in, const int* in_sizes, int n_in,
                              void* d_out, int out_size, void* d_ws, size_t ws_size,
                              hipStream_t stream) {
  const float* x      = (const float*)d_in[0];
  const float* qkv_w  = (const float*)d_in[1];
  const float* qkv_b  = (const float*)d_in[2];
  const float* proj_w = (const float*)d_in[3];
  const float* proj_b = (const float*)d_in[4];
  const float* tbl    = (const float*)d_in[5];
  float* out = (float*)d_out;

  char* ws = (char*)d_ws;
  __bf16* qkv_w_bf  = (__bf16*)ws;                  // 884,736 B
  __bf16* proj_w_bf = (__bf16*)(ws + 884736);       // 294,912 B
  float*  biasI     = (float*)(ws + 1179648);       // 196,608 B

  wa_prep<<<2496, 256, 0, stream>>>(qkv_w, proj_w, tbl, qkv_w_bf, proj_w_bf, biasI);
  wa_fused<<<2048, 256, 0, stream>>>(x, qkv_w_bf, qkv_b, proj_w_bf, proj_b, biasI, out);
}

// Round 6
// 510.765 us; speedup vs baseline: 1.1221x; 1.1221x over previous
//
#include <hip/hip_runtime.h>
#include <hip/hip_bf16.h>

#define NH 12
constexpr float SCALE = 0.17677669529663687f;  // 1/sqrt(32)

using f32x4  = __attribute__((ext_vector_type(4))) float;
using bf16x8 = __attribute__((ext_vector_type(8))) __bf16;
using u32x4  = __attribute__((ext_vector_type(4))) unsigned;

// ---------------- K0: weight bf16 conversion + bias table [12][64 i][64 j] ----
// biasI[h][i][j]: j>=49 -> -1e30 (mask padded keys), i>=49 -> 0 (don't care).
__global__ __launch_bounds__(256) void wa_prep(
    const float* __restrict__ qkv_w, const float* __restrict__ proj_w,
    const float* __restrict__ tbl,
    __bf16* __restrict__ qkv_w_bf, __bf16* __restrict__ proj_w_bf,
    float* __restrict__ biasI) {
  int p = blockIdx.x * 256 + threadIdx.x;
  if (p < 442368) { qkv_w_bf[p] = (__bf16)qkv_w[p]; return; }
  p -= 442368;
  if (p < 147456) { proj_w_bf[p] = (__bf16)proj_w[p]; return; }
  p -= 147456;
  if (p >= 49152) return;
  int h = p >> 12, rem = p & 4095, i = rem >> 6, j = rem & 63;
  float v;
  if (j >= 49) v = -1e30f;
  else if (i >= 49) v = 0.0f;
  else {
    int py = i / 7, px = i % 7, qy = j / 7, qx = j % 7;
    v = tbl[((py - qy + 6) * 13 + (px - qx + 6)) * NH + h];
  }
  biasI[p] = v;
}

__device__ inline unsigned pk_bf16(float a, float b) {
  unsigned r;
  asm("v_cvt_pk_bf16_f32 %0, %1, %2" : "=v"(r) : "v"(a), "v"(b));
  return r;  // lo16 = bf16(a), hi16 = bf16(b)
}

// half-exchange (packed): C-frag pair (rows 0-15 in lo, 16-31 in hi; lane holds
// col=lr, rows 4*ls+r) -> operand frag (lane holds its col's k-rows 8ls..8ls+7).
// 4 cvt_pk + 8 ds_bpermute + 4 selects (was 8 cvt + 16 bpermute + 8 sel).
__device__ inline bf16x8 half_ex(f32x4 lo, f32x4 hi, int baA, int baB, bool sel) {
  int l01 = (int)pk_bf16(lo[0], lo[1]), l23 = (int)pk_bf16(lo[2], lo[3]);
  int h01 = (int)pk_bf16(hi[0], hi[1]), h23 = (int)pk_bf16(hi[2], hi[3]);
  int w0a = __builtin_amdgcn_ds_bpermute(baA, l01);
  int w0b = __builtin_amdgcn_ds_bpermute(baA, h01);
  int w1a = __builtin_amdgcn_ds_bpermute(baA, l23);
  int w1b = __builtin_amdgcn_ds_bpermute(baA, h23);
  int w2a = __builtin_amdgcn_ds_bpermute(baB, l01);
  int w2b = __builtin_amdgcn_ds_bpermute(baB, h01);
  int w3a = __builtin_amdgcn_ds_bpermute(baB, l23);
  int w3b = __builtin_amdgcn_ds_bpermute(baB, h23);
  u32x4 w;
  w[0] = (unsigned)(sel ? w0b : w0a);
  w[1] = (unsigned)(sel ? w1b : w1a);
  w[2] = (unsigned)(sel ? w2b : w2a);
  w[3] = (unsigned)(sel ? w3b : w3a);
  return __builtin_bit_cast(bf16x8, w);
}

#define MFMA(a, b, c) __builtin_amdgcn_mfma_f32_16x16x32_bf16(a, b, c, 0, 0, 0)

// ---------------- fused: qkv GEMM + attention + proj, 1 block = 1 window ------
// 4 waves; wave wv owns heads {wv, wv+4, wv+8}. Phase-split per head to keep
// peak VGPR pressure ~140 (round-5 version spilled ~670MB of scratch traffic):
// A) K-loop cq,ck -> qb,ka   B) S^T = K@Q^T   C) bias+exp, f32 row-sums, pb
// D) K-loop cv (=x@Wv^T)     E) PV^T          F) normalize -> Hs
// Then 1 barrier + per-wave proj GEMM (96 cols) with Wp from L2.
__global__ __launch_bounds__(256, 2) void wa_fused(
    const float* __restrict__ x, const __bf16* __restrict__ wqkv,
    const float* __restrict__ qkv_b, const __bf16* __restrict__ wp,
    const float* __restrict__ proj_b, const float* __restrict__ biasI,
    float* __restrict__ out) {
  __shared__ __bf16 As[49 * 384];   // 36.75KB x-tile, chunk^(row&7) swizzle
  __shared__ __bf16 Hs[49 * 384];   // 36.75KB head-output tile, same swizzle
  const int t = threadIdx.x, lane = t & 63, wv = t >> 6;
  const int lr = lane & 15, ls = lane >> 4;
  const int w = blockIdx.x, w49 = w * 49;
  const int srcA = (lane & 15) | ((lane & 16) << 1);
  const int baA = srcA << 2, baB = (srcA + 16) << 2;
  const bool sel = (lane & 32) != 0;
  const f32x4 zero = {0.f, 0.f, 0.f, 0.f};

  // stage x -> As (fp32 -> bf16)
  for (int p = t; p < 2352; p += 256) {
    int row = p / 48, c = p - row * 48;
    const float* src = x + (size_t)(w49 + row) * 384 + c * 8;
    float4 a = *(const float4*)src;
    float4 b = *(const float4*)(src + 4);
    bf16x8 o;
    o[0] = (__bf16)a.x; o[1] = (__bf16)a.y; o[2] = (__bf16)a.z; o[3] = (__bf16)a.w;
    o[4] = (__bf16)b.x; o[5] = (__bf16)b.y; o[6] = (__bf16)b.z; o[7] = (__bf16)b.w;
    int cw = (c & ~7) | ((c & 7) ^ (row & 7));
    *(bf16x8*)(As + row * 384 + cw * 8) = o;
  }
  __syncthreads();

  // xa fragment loader (lane = token, k-chunk c = ks*4+ls)
  auto load_xa = [&](int ks, bf16x8* xa) {
    #pragma unroll
    for (int nt = 0; nt < 4; ++nt) {
      int tok = nt * 16 + lr; if (tok > 48) tok = 48;
      int c = ks * 4 + ls;
      int cw = (c & ~7) | ((c & 7) ^ (tok & 7));
      xa[nt] = *(const bf16x8*)(As + tok * 384 + cw * 8);
    }
  };

  for (int hi = 0; hi < 3; ++hi) {
    const int h = wv + hi * 4;
    // ---- Phase A: Q^T, K^T = Wq/Wk @ x^T
    bf16x8 qb[4], ka[4];
    {
      f32x4 cq[2][4] = {}, ck[2][4] = {};
      for (int ks = 0; ks < 12; ++ks) {
        bf16x8 xa[4];
        load_xa(ks, xa);
        bf16x8 wq[2], wk[2];
        #pragma unroll
        for (int mt = 0; mt < 2; ++mt) {
          int d = h * 32 + mt * 16 + lr;
          size_t off = (size_t)ks * 32 + ls * 8;
          wq[mt] = *(const bf16x8*)(wqkv + (size_t)d * 384 + off);
          wk[mt] = *(const bf16x8*)(wqkv + (size_t)(384 + d) * 384 + off);
        }
        #pragma unroll
        for (int mt = 0; mt < 2; ++mt)
          #pragma unroll
          for (int nt = 0; nt < 4; ++nt) {
            cq[mt][nt] = MFMA(wq[mt], xa[nt], cq[mt][nt]);
            ck[mt][nt] = MFMA(wk[mt], xa[nt], ck[mt][nt]);
          }
      }
      #pragma unroll
      for (int mt = 0; mt < 2; ++mt) {  // rows = d = 16mt + 4ls + r
        float4 bq = *(const float4*)(qkv_b + h * 32 + mt * 16 + ls * 4);
        float4 bk = *(const float4*)(qkv_b + 384 + h * 32 + mt * 16 + ls * 4);
        #pragma unroll
        for (int nt = 0; nt < 4; ++nt)
          #pragma unroll
          for (int r = 0; r < 4; ++r) {
            cq[mt][nt][r] += ((const float*)&bq)[r];
            ck[mt][nt][r] += ((const float*)&bk)[r];
          }
      }
      #pragma unroll
      for (int nt = 0; nt < 4; ++nt) {
        qb[nt] = half_ex(cq[0][nt], cq[1][nt], baA, baB, sel);
        ka[nt] = half_ex(ck[0][nt], ck[1][nt], baA, baB, sel);
      }
    }
    // ---- Phase B: S^T = K @ Q^T (rows j, cols i), one k-step (d=32)
    // ---- Phase C: bias + exp, f32 row sums, pack P^T operand frags
    bf16x8 pb[2][4];
    float s[4] = {0.f, 0.f, 0.f, 0.f};
    {
      f32x4 st[4][4];
      #pragma unroll
      for (int mt = 0; mt < 4; ++mt)
        #pragma unroll
        for (int nt = 0; nt < 4; ++nt)
          st[mt][nt] = MFMA(ka[mt], qb[nt], zero);
      #pragma unroll
      for (int mt = 0; mt < 4; ++mt)
        #pragma unroll
        for (int nt = 0; nt < 4; ++nt) {
          int i = nt * 16 + lr;
          float4 bi = *(const float4*)(biasI + ((size_t)h * 64 + i) * 64 + mt * 16 + ls * 4);
          #pragma unroll
          for (int r = 0; r < 4; ++r) {
            float e = __expf(fmaf(st[mt][nt][r], SCALE, ((const float*)&bi)[r]));
            st[mt][nt][r] = e;
            s[nt] += e;
          }
        }
      #pragma unroll
      for (int nt = 0; nt < 4; ++nt) {
        s[nt] += __shfl_xor(s[nt], 16, 64);
        s[nt] += __shfl_xor(s[nt], 32, 64);
      }
      #pragma unroll
      for (int k2 = 0; k2 < 2; ++k2)
        #pragma unroll
        for (int nt = 0; nt < 4; ++nt)
          pb[k2][nt] = half_ex(st[2 * k2][nt], st[2 * k2 + 1][nt], baA, baB, sel);
    }
    // ---- Phase D: V = x @ Wv^T (rows tok, cols d)
    f32x4 ot[2][4] = {};
    {
      f32x4 cv[4][2] = {};
      for (int ks = 0; ks < 12; ++ks) {
        bf16x8 xa[4];
        load_xa(ks, xa);
        bf16x8 wvb[2];
        #pragma unroll
        for (int nt = 0; nt < 2; ++nt) {
          int d = h * 32 + nt * 16 + lr;
          wvb[nt] = *(const bf16x8*)(wqkv + (size_t)(768 + d) * 384 + (size_t)ks * 32 + ls * 8);
        }
        #pragma unroll
        for (int mt = 0; mt < 4; ++mt)
          #pragma unroll
          for (int nt = 0; nt < 2; ++nt)
            cv[mt][nt] = MFMA(xa[mt], wvb[nt], cv[mt][nt]);
      }
      #pragma unroll
      for (int nt = 0; nt < 2; ++nt) {  // cols = d = 16nt + lr
        float bv = qkv_b[768 + h * 32 + nt * 16 + lr];
        #pragma unroll
        for (int mt = 0; mt < 4; ++mt)
          #pragma unroll
          for (int r = 0; r < 4; ++r) cv[mt][nt][r] += bv;
      }
      // ---- Phase E: V^T operand frags (lane = d, k = tok), PV^T
      bf16x8 va[2][2];
      #pragma unroll
      for (int ct = 0; ct < 2; ++ct)
        #pragma unroll
        for (int k2 = 0; k2 < 2; ++k2)
          va[ct][k2] = half_ex(cv[2 * k2][ct], cv[2 * k2 + 1][ct], baA, baB, sel);
      #pragma unroll
      for (int k2 = 0; k2 < 2; ++k2)
        #pragma unroll
        for (int ct = 0; ct < 2; ++ct)
          #pragma unroll
          for (int nt = 0; nt < 4; ++nt)
            ot[ct][nt] = MFMA(va[ct][k2], pb[k2][nt], ot[ct][nt]);
    }
    // ---- Phase F: normalize, convert H^T -> proj-A layout, write Hs
    #pragma unroll
    for (int nt = 0; nt < 4; ++nt) {
      float inv = 1.0f / s[nt];
      f32x4 h0, h1;
      #pragma unroll
      for (int r = 0; r < 4; ++r) { h0[r] = ot[0][nt][r] * inv; h1[r] = ot[1][nt][r] * inv; }
      bf16x8 pa = half_ex(h0, h1, baA, baB, sel);
      int i = nt * 16 + lr;
      if (i < 49) {
        int c = h * 4 + ls;
        int cw = (c & ~7) | ((c & 7) ^ (i & 7));
        *(bf16x8*)(Hs + i * 384 + cw * 8) = pa;
      }
    }
  }
  __syncthreads();  // Hs complete (all heads, all waves)

  // ---- proj: out[:, wv*96 .. +95] = Hs @ Wp^T + b, K = 384 (12 steps)
  f32x4 acc[4][6] = {};
  for (int ks = 0; ks < 12; ++ks) {
    bf16x8 ha[4], wb[6];
    #pragma unroll
    for (int it = 0; it < 4; ++it) {
      int tok = it * 16 + lr; if (tok > 48) tok = 48;
      int c = ks * 4 + ls;
      int cw = (c & ~7) | ((c & 7) ^ (tok & 7));
      ha[it] = *(const bf16x8*)(Hs + tok * 384 + cw * 8);
    }
    #pragma unroll
    for (int ct = 0; ct < 6; ++ct) {
      int n = wv * 96 + ct * 16 + lr;
      wb[ct] = *(const bf16x8*)(wp + (size_t)n * 384 + ks * 32 + ls * 8);
    }
    #pragma unroll
    for (int it = 0; it < 4; ++it)
      #pragma unroll
      for (int ct = 0; ct < 6; ++ct)
        acc[it][ct] = MFMA(ha[it], wb[ct], acc[it][ct]);
  }
  float pbias[6];
  #pragma unroll
  for (int ct = 0; ct < 6; ++ct) pbias[ct] = proj_b[wv * 96 + ct * 16 + lr];
  #pragma unroll
  for (int it = 0; it < 4; ++it)
    #pragma unroll
    for (int r = 0; r < 4; ++r) {
      int i = it * 16 + ls * 4 + r;
      if (i < 49) {
        float* dst = out + (size_t)(w49 + i) * 384 + wv * 96;
        #pragma unroll
        for (int ct = 0; ct < 6; ++ct)
          dst[ct * 16 + lr] = acc[it][ct][r] + pbias[ct];
      }
    }
}

extern "C" void kernel_launch(void* const* d_in, const int* in_sizes, int n_in,
                              void* d_out, int out_size, void* d_ws, size_t ws_size,
                              hipStream_t stream) {
  const float* x      = (const float*)d_in[0];
  const float* qkv_w  = (const float*)d_in[1];
  const float* qkv_b  = (const float*)d_in[2];
  const float* proj_w = (const float*)d_in[3];
  const float* proj_b = (const float*)d_in[4];
  const float* tbl    = (const float*)d_in[5];
  float* out = (float*)d_out;

  char* ws = (char*)d_ws;
  __bf16* qkv_w_bf  = (__bf16*)ws;                  // 884,736 B
  __bf16* proj_w_bf = (__bf16*)(ws + 884736);       // 294,912 B
  float*  biasI     = (float*)(ws + 1179648);       // 196,608 B

  wa_prep<<<2496, 256, 0, stream>>>(qkv_w, proj_w, tbl, qkv_w_bf, proj_w_bf, biasI);
  wa_fused<<<2048, 256, 0, stream>>>(x, qkv_w_bf, qkv_b, proj_w_bf, proj_b, biasI, out);
}